// Round 1
// baseline (98.608 us; speedup 1.0000x reference)
//
#include <hip/hip_runtime.h>
#include <hip/hip_bf16.h>

// loss = -(1/B) * sum_{b,c} preds_t[b,c] * log(preds_s[b,c])
// B=4096, C=1000, fp32 in, fp32 scalar out. Memory-bound: 32.77 MB read.

#define BLOCK 256
#define GRID  2048   // 8 blocks/CU on 256 CUs; grid-stride covers n

__global__ __launch_bounds__(BLOCK) void kd_loss_kernel(
    const float* __restrict__ preds_s,
    const float* __restrict__ preds_t,
    float* __restrict__ out,
    int n,        // total elements (B*C)
    float scale)  // -1/B
{
    const int n4 = n >> 2;                 // float4 count
    const float4* s4 = (const float4*)preds_s;
    const float4* t4 = (const float4*)preds_t;

    float acc = 0.0f;
    for (int i = blockIdx.x * BLOCK + threadIdx.x; i < n4;
         i += gridDim.x * BLOCK) {
        float4 a = s4[i];
        float4 b = t4[i];
        acc += b.x * __logf(a.x);
        acc += b.y * __logf(a.y);
        acc += b.z * __logf(a.z);
        acc += b.w * __logf(a.w);
    }

    // scalar tail (n % 4), handled by first threads of block 0
    int tail_start = n4 << 2;
    if (blockIdx.x == 0) {
        for (int i = tail_start + threadIdx.x; i < n; i += BLOCK)
            acc += preds_t[i] * __logf(preds_s[i]);
    }

    // wave-64 butterfly reduce
    #pragma unroll
    for (int off = 32; off > 0; off >>= 1)
        acc += __shfl_down(acc, off, 64);

    // cross-wave reduce via LDS (BLOCK/64 = 4 waves)
    __shared__ float wsum[BLOCK / 64];
    const int lane = threadIdx.x & 63;
    const int wid  = threadIdx.x >> 6;
    if (lane == 0) wsum[wid] = acc;
    __syncthreads();

    if (threadIdx.x == 0) {
        float r = 0.0f;
        #pragma unroll
        for (int w = 0; w < BLOCK / 64; ++w) r += wsum[w];
        atomicAdd(out, r * scale);   // device-scope by default on CDNA
    }
}

extern "C" void kernel_launch(void* const* d_in, const int* in_sizes, int n_in,
                              void* d_out, int out_size, void* d_ws, size_t ws_size,
                              hipStream_t stream) {
    const float* preds_s = (const float*)d_in[0];
    const float* preds_t = (const float*)d_in[1];
    float* out = (float*)d_out;

    const int n = in_sizes[0];      // B*C = 4096*1000
    const int B = 4096;             // fixed by the problem
    const float scale = -1.0f / (float)B;

    // d_out is re-poisoned to 0xAA before every timed replay: zero it.
    hipMemsetAsync(out, 0, out_size * sizeof(float), stream);

    kd_loss_kernel<<<GRID, BLOCK, 0, stream>>>(preds_s, preds_t, out, n, scale);
}

// Round 2
// 75.039 us; speedup vs baseline: 1.3141x; 1.3141x over previous
//
#include <hip/hip_runtime.h>
#include <hip/hip_bf16.h>

// loss = -(1/B) * sum_{b,c} preds_t[b,c] * log(preds_s[b,c])
// B=4096, C=1000, fp32 in, fp32 scalar out. Memory-bound: 32.77 MB read.
// R2: atomic-free two-kernel reduction. Kernel1 -> d_ws partials (plain
// stores over poison), kernel2 reduces partials and writes scaled result
// (no d_out memset needed). Eliminates 2048 same-address device-scope
// atomics and the extra memset dispatch from R1.

#define BLOCK 256
#define GRID1 1024   // 4 blocks/CU; 16 waves/CU — enough to saturate HBM

__global__ __launch_bounds__(BLOCK) void kd_partial_kernel(
    const float* __restrict__ preds_s,
    const float* __restrict__ preds_t,
    float* __restrict__ partials,   // d_ws, GRID1 floats
    int n)                          // total elements (B*C)
{
    const int n4 = n >> 2;
    const float4* s4 = (const float4*)preds_s;
    const float4* t4 = (const float4*)preds_t;

    float acc = 0.0f;
    for (int i = blockIdx.x * BLOCK + threadIdx.x; i < n4;
         i += GRID1 * BLOCK) {
        float4 a = s4[i];
        float4 b = t4[i];
        acc += b.x * __logf(a.x);
        acc += b.y * __logf(a.y);
        acc += b.z * __logf(a.z);
        acc += b.w * __logf(a.w);
    }

    // scalar tail (n % 4 != 0), block 0 only; empty for n = 4,096,000
    if (blockIdx.x == 0) {
        for (int i = (n4 << 2) + threadIdx.x; i < n; i += BLOCK)
            acc += preds_t[i] * __logf(preds_s[i]);
    }

    // wave-64 butterfly reduce
    #pragma unroll
    for (int off = 32; off > 0; off >>= 1)
        acc += __shfl_down(acc, off, 64);

    __shared__ float wsum[BLOCK / 64];
    const int lane = threadIdx.x & 63;
    const int wid  = threadIdx.x >> 6;
    if (lane == 0) wsum[wid] = acc;
    __syncthreads();

    if (threadIdx.x == 0) {
        float r = 0.0f;
        #pragma unroll
        for (int w = 0; w < BLOCK / 64; ++w) r += wsum[w];
        partials[blockIdx.x] = r;    // plain store — no init required
    }
}

__global__ __launch_bounds__(BLOCK) void kd_final_kernel(
    const float* __restrict__ partials,  // GRID1 floats
    float* __restrict__ out,
    float scale)                         // -1/B
{
    // GRID1 = 1024 partials = 256 threads x float4
    const float4* p4 = (const float4*)partials;
    float4 v = p4[threadIdx.x];
    float acc = v.x + v.y + v.z + v.w;

    #pragma unroll
    for (int off = 32; off > 0; off >>= 1)
        acc += __shfl_down(acc, off, 64);

    __shared__ float wsum[BLOCK / 64];
    const int lane = threadIdx.x & 63;
    const int wid  = threadIdx.x >> 6;
    if (lane == 0) wsum[wid] = acc;
    __syncthreads();

    if (threadIdx.x == 0) {
        float r = 0.0f;
        #pragma unroll
        for (int w = 0; w < BLOCK / 64; ++w) r += wsum[w];
        out[0] = r * scale;   // fully overwrites d_out — no memset needed
    }
}

extern "C" void kernel_launch(void* const* d_in, const int* in_sizes, int n_in,
                              void* d_out, int out_size, void* d_ws, size_t ws_size,
                              hipStream_t stream) {
    const float* preds_s = (const float*)d_in[0];
    const float* preds_t = (const float*)d_in[1];
    float* out = (float*)d_out;
    float* partials = (float*)d_ws;     // 1024 floats = 4 KB << ws_size

    const int n = in_sizes[0];          // B*C = 4096*1000
    const int B = 4096;                 // fixed by the problem
    const float scale = -1.0f / (float)B;

    kd_partial_kernel<<<GRID1, BLOCK, 0, stream>>>(preds_s, preds_t, partials, n);
    kd_final_kernel<<<1, BLOCK, 0, stream>>>(partials, out, scale);
}